// Round 7
// baseline (149.299 us; speedup 1.0000x reference)
//
#include <hip/hip_runtime.h>
#include <stdint.h>

// Problem constants (static per reference)
#define NG    256    // graphs
#define NPG   128    // nodes per graph
#define PP    8      // perturbations
#define IND   64     // input dim
#define HID   128    // hidden
#define OUTD  10     // classes

typedef short bf16x8 __attribute__((ext_vector_type(8)));
typedef float f32x4  __attribute__((ext_vector_type(4)));

// RNE f32->bf16 (bit trick) — the verified-correct conversion on this path.
static __device__ __forceinline__ unsigned short f2bf(float f) {
    unsigned int u = __float_as_uint(f);
    u += 0x7FFFu + ((u >> 16) & 1u);
    return (unsigned short)(u >> 16);
}

static __device__ __forceinline__ f32x4 mfma16(bf16x8 a, bf16x8 b, f32x4 c) {
    return __builtin_amdgcn_mfma_f32_16x16x32_bf16(a, b, c, 0, 0, 0);
}

// ws layout (shorts) — weights only:
//   [0)      W1t  128x64   (Wt[out][in])
//   [8192)   W2t  128x128
//   [24576)  Wg1t 128x128
//   [40960)  Wg2t 128x128
//   [57344)  Wb1t 128x128
//   [73728)  Wb2t 128x128

#define LSTR 136   // bf16 LDS row stride for 128-col tiles (272 B): 68 words
                   // == 4 mod 32 -> only 2-way bank aliasing (free)
#define XBS  72    // x-slab stride (64 cols + pad): 36 words == 4 mod 32, same

// ---------------------------------------------------------------------------
// Kernel 0: convert + transpose weights (coalesced writes; src stays in L2)
// ---------------------------------------------------------------------------
__global__ void prep_weights(const float* __restrict__ Wl1, const float* __restrict__ Wl2,
                             const float* __restrict__ Wg1, const float* __restrict__ Wg2,
                             const float* __restrict__ Wb1, const float* __restrict__ Wb2,
                             unsigned short* __restrict__ ws) {
    int e = blockIdx.x * blockDim.x + threadIdx.x;
    if (e < 8192) {
        int n = e >> 6, k = e & 63;
        ws[e] = f2bf(Wl1[k * HID + n]);
        return;
    }
    int e2 = e - 8192;
    int m = e2 >> 14;
    int idx = e2 & 16383;
    int n = idx >> 7, k = idx & 127;
    const float* src;
    if      (m == 0) src = Wl2;
    else if (m == 1) src = Wg1;
    else if (m == 2) src = Wg2;
    else if (m == 3) src = Wb1;
    else             src = Wb2;
    ws[8192 + m * 16384 + idx] = f2bf(src[k * HID + n]);
}

// ---------------------------------------------------------------------------
// Fused kernel: ONE BLOCK PER GRAPH (256 blocks x 512 threads = 8 waves).
// Round-7 change vs round-6: h1 double-buffered (h1a/h1b alternate per tile)
// and the per-tile agg slice lives in registers (bf16-packed, statically
// indexed via full unroll). This cuts phase A to ONE barrier per tile:
//   L1(nt)->h1[nt&1]; stage next x; BARRIER; L2(nt) reads h1[nt&1]
// Next tile's L1 targets the other h1 buffer, so it (and x staging) overlap
// slower waves' L2 of the current tile. Race audit:
//  - L1(nt) reads xb[nt&1], written by XWRITE in iter nt-1 (pre-barrier(nt-1)).
//  - XWRITE(xb[(nt+1)&1]) in iter nt: last readers were L1(nt-1), done before
//    barrier(nt-1). Disjoint from concurrent L1(nt)/L2(nt-1) accesses.
//  - L1(nt+1) writes h1[(nt+1)&1], disjoint from L2(nt) reads of h1[nt&1].
//  - agg: lane-exclusive registers; final store to h1a only conflicts with
//    L2(7) reads of h1b (disjoint), then a barrier precedes phase B.
// Arithmetic unchanged: same f2bf sites, same values, same order -> bit-
// identical to the round-6 passing kernel. LDS 107328 B, 1 block/CU.
// ---------------------------------------------------------------------------
__global__ __launch_bounds__(512) void graph_fused(
    const float* __restrict__ x,
    const unsigned short* __restrict__ wt,
    const float* __restrict__ bl1, const float* __restrict__ bl2,
    const float* __restrict__ bg1, const float* __restrict__ bg2,
    const float* __restrict__ bb1, const float* __restrict__ bb2,
    const float* __restrict__ Wd1, const float* __restrict__ bd1,
    const float* __restrict__ Wd2, const float* __restrict__ bd2,
    float* __restrict__ out)
{
    // LDS map (bytes):
    //   [0)      xb0 128*XBS shorts (18432)
    //   [18432)  xb1 128*XBS shorts (18432)
    //   [36864)  h1a 128*LSTR shorts (34816)   } phase-A L1 dbuf;
    //   [71680)  h1b 128*LSTR shorts (34816)   } phase-B ping-pong
    //   [106496) pool 128 f32 (512)
    //   [107008) z    64 f32  (256)
    //   [107264) zz   16 f32  (64)
    __shared__ __align__(16) unsigned char smem[107328];
    unsigned short* xb0 = (unsigned short*)(smem);
    unsigned short* xb1 = (unsigned short*)(smem + 18432);
    unsigned short* h1a = (unsigned short*)(smem + 36864);
    unsigned short* h1b = (unsigned short*)(smem + 71680);
    float* pool = (float*)(smem + 106496);
    float* z    = (float*)(smem + 107008);
    float* zz   = (float*)(smem + 107264);

    const int g    = blockIdx.x;
    const int tid  = threadIdx.x;
    const int wave = tid >> 6;     // 0..7
    const int lane = tid & 63;
    const int q    = lane >> 4;
    const int r    = lane & 15;
    const int ot   = wave;         // each wave owns output cols [16*ot, 16*ot+16)

    const float* xg = x + (size_t)g * (NPG * PP) * IND;

    // ---- per-thread staging geometry: 8192 elems/tile, 16 per thread ----
    int sIt[4], cIt[4], gRow[4];
#pragma unroll
    for (int it = 0; it < 4; ++it) {
        int e = it * 2048 + tid * 4;       // element index in the tile slab
        int s = e >> 6;                    // LDS row (p*16 + rr)
        sIt[it]  = s;
        cIt[it]  = e & 63;
        gRow[it] = (s >> 4) * 128 + (s & 15);   // global row sans nt*16
    }
    float4 ld[4];

#define ISSUE(t)                                                              \
    do {                                                                      \
        _Pragma("unroll")                                                     \
        for (int it = 0; it < 4; ++it)                                        \
            ld[it] = *(const float4*)(xg + (size_t)(gRow[it] + (t) * 16) * IND + cIt[it]); \
    } while (0)

#define XWRITE(dst)                                                           \
    do {                                                                      \
        _Pragma("unroll")                                                     \
        for (int it = 0; it < 4; ++it) {                                      \
            ushort4 w4;                                                       \
            w4.x = f2bf(ld[it].x); w4.y = f2bf(ld[it].y);                     \
            w4.z = f2bf(ld[it].z); w4.w = f2bf(ld[it].w);                     \
            *(ushort4*)(&(dst)[sIt[it] * XBS + cIt[it]]) = w4;                \
        }                                                                     \
    } while (0)

    // ---- weight fragments (loads overlap the tile-0 staging) ----
    bf16x8 w1f[2];
#pragma unroll
    for (int ks = 0; ks < 2; ++ks)
        w1f[ks] = *(const bf16x8*)(wt + (ot * 16 + r) * 64 + ks * 32 + q * 8);

    const unsigned short* w2t = wt + 8192;
    bf16x8 w2f[4];
#pragma unroll
    for (int ks = 0; ks < 4; ++ks)
        w2f[ks] = *(const bf16x8*)(w2t + (ot * 16 + r) * 128 + ks * 32 + q * 8);

    const float4 b1s = *(const float4*)(bl1 + ot * 16 + q * 4);
    const float4 b2s = *(const float4*)(bl2 + ot * 16 + q * 4);

    // ---- prologue: tile 0 staged, tile 1 in flight ----
    ISSUE(0);
    XWRITE(xb0);
    ISSUE(1);
    __syncthreads();

    // ======================= phase A: 8 node-tiles =========================
    ushort4 aggv[8];   // bf16-packed agg slice per tile (static-indexed)

#pragma unroll
    for (int nt = 0; nt < 8; ++nt) {
        unsigned short* xcur = (nt & 1) ? xb1 : xb0;
        unsigned short* hcur = (nt & 1) ? h1b : h1a;

        // layer 1 (K=64) for all 8 perturbations of this tile -> hcur
#pragma unroll
        for (int p = 0; p < PP; ++p) {
            f32x4 a0 = (f32x4){0.f, 0.f, 0.f, 0.f};
#pragma unroll
            for (int ks = 0; ks < 2; ++ks) {
                bf16x8 xf = *(const bf16x8*)(&xcur[(p * 16 + r) * XBS + ks * 32 + q * 8]);
                a0 = mfma16(w1f[ks], xf, a0);
            }
            ushort4 v0;
            v0.x = f2bf(fmaxf(a0[0] + b1s.x, 0.f));
            v0.y = f2bf(fmaxf(a0[1] + b1s.y, 0.f));
            v0.z = f2bf(fmaxf(a0[2] + b1s.z, 0.f));
            v0.w = f2bf(fmaxf(a0[3] + b1s.w, 0.f));
            *(ushort4*)(&hcur[(p * 16 + r) * LSTR + ot * 16 + q * 4]) = v0;
        }

        // stage next tile's x (regs already hold it) + refill two ahead.
        // Pre-barrier: xb[(nt+1)&1]'s last readers (L1(nt-1)) finished before
        // barrier(nt-1); concurrent L1(nt)/L2(nt-1) touch disjoint buffers.
        if (nt < 7) {
            if (nt & 1) XWRITE(xb0); else XWRITE(xb1);
        }
        if (nt < 6) ISSUE(nt + 2);

        __syncthreads();   // hcur complete; next-x staged

        // layer 2 (K=128), relu-accumulate over perturbations -> regs
        f32x4 agg0 = (f32x4){0.f, 0.f, 0.f, 0.f};
#pragma unroll
        for (int p = 0; p < PP; ++p) {
            f32x4 c0 = (f32x4){0.f, 0.f, 0.f, 0.f};
#pragma unroll
            for (int ks = 0; ks < 4; ++ks) {
                bf16x8 hf = *(const bf16x8*)(&hcur[(p * 16 + r) * LSTR + ks * 32 + q * 8]);
                c0 = mfma16(w2f[ks], hf, c0);
            }
            agg0[0] += fmaxf(c0[0] + b2s.x, 0.f);
            agg0[1] += fmaxf(c0[1] + b2s.y, 0.f);
            agg0[2] += fmaxf(c0[2] + b2s.z, 0.f);
            agg0[3] += fmaxf(c0[3] + b2s.w, 0.f);
        }
        aggv[nt].x = f2bf(agg0[0]);
        aggv[nt].y = f2bf(agg0[1]);
        aggv[nt].z = f2bf(agg0[2]);
        aggv[nt].w = f2bf(agg0[3]);
    }

    // materialize agg into h1a (free: L2(7) reads h1b; L2(6)'s h1a reads
    // finished before barrier(7)); lane-exclusive 8B regions.
#pragma unroll
    for (int nt = 0; nt < 8; ++nt)
        *(ushort4*)(&h1a[(nt * 16 + r) * LSTR + ot * 16 + q * 4]) = aggv[nt];
    __syncthreads();

    // ================= phase B: 4x (Linear+ReLU) + pool ====================
    int cur = 0;
#pragma unroll
    for (int l = 0; l < 4; ++l) {
        const unsigned short* wl = wt + 24576 + l * 16384;
        const float* bl = (l == 0) ? bg1 : (l == 1) ? bg2 : (l == 2) ? bb1 : bb2;

        bf16x8 wf[4];
#pragma unroll
        for (int ks = 0; ks < 4; ++ks)
            wf[ks] = *(const bf16x8*)(wl + (ot * 16 + r) * 128 + ks * 32 + q * 8);

        unsigned short* Xb = cur ? h1b : h1a;
        unsigned short* Yb = cur ? h1a : h1b;

        f32x4 acc[8];
#pragma unroll
        for (int j = 0; j < 8; ++j)
            acc[j] = (f32x4){0.f, 0.f, 0.f, 0.f};

#pragma unroll
        for (int ks = 0; ks < 4; ++ks) {
#pragma unroll
            for (int j = 0; j < 8; ++j) {
                bf16x8 xf = *(const bf16x8*)(&Xb[(j * 16 + r) * LSTR + ks * 32 + q * 8]);
                acc[j] = mfma16(wf[ks], xf, acc[j]);
            }
        }

        if (l < 3) {
            float4 bs = *(const float4*)(bl + ot * 16 + q * 4);
#pragma unroll
            for (int j = 0; j < 8; ++j) {
                ushort4 v;
                v.x = f2bf(fmaxf(acc[j][0] + bs.x, 0.f));
                v.y = f2bf(fmaxf(acc[j][1] + bs.y, 0.f));
                v.z = f2bf(fmaxf(acc[j][2] + bs.z, 0.f));
                v.w = f2bf(fmaxf(acc[j][3] + bs.w, 0.f));
                *(ushort4*)(&Yb[(j * 16 + r) * LSTR + ot * 16 + q * 4]) = v;
            }
            __syncthreads();
            cur ^= 1;
        } else {
            float4 bs = *(const float4*)(bl + ot * 16 + q * 4);
            float s0 = 0.f, s1 = 0.f, s2 = 0.f, s3 = 0.f;
#pragma unroll
            for (int j = 0; j < 8; ++j) {
                s0 += fmaxf(acc[j][0] + bs.x, 0.f);
                s1 += fmaxf(acc[j][1] + bs.y, 0.f);
                s2 += fmaxf(acc[j][2] + bs.z, 0.f);
                s3 += fmaxf(acc[j][3] + bs.w, 0.f);
            }
#pragma unroll
            for (int m = 1; m < 16; m <<= 1) {
                s0 += __shfl_xor(s0, m, 64);
                s1 += __shfl_xor(s1, m, 64);
                s2 += __shfl_xor(s2, m, 64);
                s3 += __shfl_xor(s3, m, 64);
            }
            if (r == 0) {
                pool[ot * 16 + q * 4 + 0] = s0;   // exclusive cols per wave
                pool[ot * 16 + q * 4 + 1] = s1;
                pool[ot * 16 + q * 4 + 2] = s2;
                pool[ot * 16 + q * 4 + 3] = s3;
            }
        }
    }
    __syncthreads();

    // ===================== decoder + log_softmax ===========================
    if (tid < 64) {
        float a0 = bd1[tid], a1 = 0.f, a2 = 0.f, a3 = 0.f;
#pragma unroll
        for (int k = 0; k < 128; k += 4) {
            a0 += pool[k]     * Wd1[(k)     * 64 + tid];
            a1 += pool[k + 1] * Wd1[(k + 1) * 64 + tid];
            a2 += pool[k + 2] * Wd1[(k + 2) * 64 + tid];
            a3 += pool[k + 3] * Wd1[(k + 3) * 64 + tid];
        }
        z[tid] = fmaxf((a0 + a1) + (a2 + a3), 0.f);
    }
    __syncthreads();
    if (tid < OUTD) {
        float b0 = bd2[tid], b1 = 0.f;
#pragma unroll
        for (int k = 0; k < 64; k += 2) {
            b0 += z[k]     * Wd2[(k)     * OUTD + tid];
            b1 += z[k + 1] * Wd2[(k + 1) * OUTD + tid];
        }
        zz[tid] = b0 + b1;
    }
    __syncthreads();
    if (tid == 0) {
        float m = -1e30f;
#pragma unroll
        for (int j = 0; j < OUTD; ++j) m = fmaxf(m, zz[j]);
        float ssum = 0.f;
#pragma unroll
        for (int j = 0; j < OUTD; ++j) ssum += expf(zz[j] - m);
        float ls = logf(ssum);
#pragma unroll
        for (int j = 0; j < OUTD; ++j) out[g * OUTD + j] = zz[j] - m - ls;
    }
#undef ISSUE
#undef XWRITE
}

extern "C" void kernel_launch(void* const* d_in, const int* in_sizes, int n_in,
                              void* d_out, int out_size, void* d_ws, size_t ws_size,
                              hipStream_t stream) {
    const float* x   = (const float*)d_in[0];
    // d_in[1] = ptr (unused; structure is static)
    const float* Wl1 = (const float*)d_in[2];
    const float* bl1 = (const float*)d_in[3];
    const float* Wl2 = (const float*)d_in[4];
    const float* bl2 = (const float*)d_in[5];
    const float* Wg1 = (const float*)d_in[6];
    const float* bg1 = (const float*)d_in[7];
    const float* Wg2 = (const float*)d_in[8];
    const float* bg2 = (const float*)d_in[9];
    const float* Wb1 = (const float*)d_in[10];
    const float* bb1 = (const float*)d_in[11];
    const float* Wb2 = (const float*)d_in[12];
    const float* bb2 = (const float*)d_in[13];
    const float* Wd1 = (const float*)d_in[14];
    const float* bd1 = (const float*)d_in[15];
    const float* Wd2 = (const float*)d_in[16];
    const float* bd2 = (const float*)d_in[17];

    unsigned short* ws = (unsigned short*)d_ws;

    prep_weights<<<352, 256, 0, stream>>>(Wl1, Wl2, Wg1, Wg2, Wb1, Wb2, ws);
    graph_fused<<<NG, 512, 0, stream>>>(x, ws, bl1, bl2, bg1, bg2, bb1, bb2,
                                        Wd1, bd1, Wd2, bd2, (float*)d_out);
}

// Round 8
// 144.919 us; speedup vs baseline: 1.0302x; 1.0302x over previous
//
#include <hip/hip_runtime.h>
#include <stdint.h>

// Problem constants (static per reference)
#define NG    256    // graphs
#define NPG   128    // nodes per graph
#define PP    8      // perturbations
#define IND   64     // input dim
#define HID   128    // hidden
#define OUTD  10     // classes

typedef short bf16x8 __attribute__((ext_vector_type(8)));
typedef float f32x4  __attribute__((ext_vector_type(4)));

// RNE f32->bf16 (bit trick) — the verified-correct conversion on this path.
static __device__ __forceinline__ unsigned short f2bf(float f) {
    unsigned int u = __float_as_uint(f);
    u += 0x7FFFu + ((u >> 16) & 1u);
    return (unsigned short)(u >> 16);
}

static __device__ __forceinline__ f32x4 mfma16(bf16x8 a, bf16x8 b, f32x4 c) {
    return __builtin_amdgcn_mfma_f32_16x16x32_bf16(a, b, c, 0, 0, 0);
}

// ws layout (shorts) — weights only:
//   [0)      W1t  128x64   (Wt[out][in])
//   [8192)   W2t  128x128
//   [24576)  Wg1t 128x128
//   [40960)  Wg2t 128x128
//   [57344)  Wb1t 128x128
//   [73728)  Wb2t 128x128

#define LSTR 136   // bf16 LDS row stride for 128-col tiles (272 B): 68 words
                   // == 4 mod 32 -> only 2-way bank aliasing (free)
#define XBS  72    // x-slab stride (64 cols + pad): 36 words == 4 mod 32, same

// ---------------------------------------------------------------------------
// Kernel 0: convert + transpose weights (coalesced writes; src stays in L2)
// ---------------------------------------------------------------------------
__global__ void prep_weights(const float* __restrict__ Wl1, const float* __restrict__ Wl2,
                             const float* __restrict__ Wg1, const float* __restrict__ Wg2,
                             const float* __restrict__ Wb1, const float* __restrict__ Wb2,
                             unsigned short* __restrict__ ws) {
    int e = blockIdx.x * blockDim.x + threadIdx.x;
    if (e < 8192) {
        int n = e >> 6, k = e & 63;
        ws[e] = f2bf(Wl1[k * HID + n]);
        return;
    }
    int e2 = e - 8192;
    int m = e2 >> 14;
    int idx = e2 & 16383;
    int n = idx >> 7, k = idx & 127;
    const float* src;
    if      (m == 0) src = Wl2;
    else if (m == 1) src = Wg1;
    else if (m == 2) src = Wg2;
    else if (m == 3) src = Wb1;
    else             src = Wb2;
    ws[8192 + m * 16384 + idx] = f2bf(src[k * HID + n]);
}

// ---------------------------------------------------------------------------
// Fused kernel: ONE BLOCK PER GRAPH, 1024 threads = 16 waves = 4 waves/SIMD.
// Round-8 change vs round-7: round-7 counters showed the kernel is latency-
// bound at 2 waves/SIMD (Occupancy 19%, HBM 10%, Mfma 15%). Double the wave
// count with a TWO-TEAM block: team 0 (waves 0-7) processes even node-tiles,
// team 1 (waves 8-15) odd tiles, concurrently. Same 107328 B LDS: the former
// xb0/xb1 are now per-team x buffers, h1a/h1b per-team h1 buffers. Teams are
// symmetric, so block-wide __syncthreads() hits identical program points.
// Per-tile arithmetic is the exact round-6/7 code run by a full 8-wave team
// -> bit-identical output. Phase B + decoder run on team 0 only (team 1
// idles through barriers).
// Phase-A iteration i (tiles 2i and 2i+1 in parallel):
//   L1: read xbt -> h1t ; BARRIER ; L2: read h1t -> agg regs ;
//   XWRITE next tile into xbt (readers finished at the barrier) ;
//   ISSUE tile T+4 (regs, 1 full iteration of latency cover) ; BARRIER
// ---------------------------------------------------------------------------
__global__ __launch_bounds__(1024) void graph_fused(
    const float* __restrict__ x,
    const unsigned short* __restrict__ wt,
    const float* __restrict__ bl1, const float* __restrict__ bl2,
    const float* __restrict__ bg1, const float* __restrict__ bg2,
    const float* __restrict__ bb1, const float* __restrict__ bb2,
    const float* __restrict__ Wd1, const float* __restrict__ bd1,
    const float* __restrict__ Wd2, const float* __restrict__ bd2,
    float* __restrict__ out)
{
    // LDS map (bytes):
    //   [0)      xb team0 128*XBS shorts (18432)
    //   [18432)  xb team1 128*XBS shorts (18432)
    //   [36864)  h1 team0 = h1a 128*LSTR shorts (34816)  } phase-B ping-pong
    //   [71680)  h1 team1 = h1b 128*LSTR shorts (34816)  }
    //   [106496) pool 128 f32 (512)
    //   [107008) z    64 f32  (256)
    //   [107264) zz   16 f32  (64)
    __shared__ __align__(16) unsigned char smem[107328];

    const int g    = blockIdx.x;
    const int tid  = threadIdx.x;
    const int wave = tid >> 6;      // 0..15
    const int team = wave >> 3;     // 0: even tiles, 1: odd tiles
    const int lt   = tid & 511;     // team-local thread id (512 per team)
    const int lane = tid & 63;
    const int q    = lane >> 4;
    const int r    = lane & 15;
    const int ot   = wave & 7;      // output-col tile within the team

    unsigned short* xbt = (unsigned short*)(smem + team * 18432);
    unsigned short* h1t = (unsigned short*)(smem + 36864 + team * 34816);
    unsigned short* h1a = (unsigned short*)(smem + 36864);
    unsigned short* h1b = (unsigned short*)(smem + 71680);
    float* pool = (float*)(smem + 106496);
    float* z    = (float*)(smem + 107008);
    float* zz   = (float*)(smem + 107264);

    const float* xg = x + (size_t)g * (NPG * PP) * IND;

    // ---- per-team staging geometry: 8192 elems/tile over 512 threads ----
    int sIt[4], cIt[4], gRow[4];
#pragma unroll
    for (int it = 0; it < 4; ++it) {
        int e = it * 2048 + lt * 4;        // element index in the tile slab
        int s = e >> 6;                    // LDS row (p*16 + rr)
        sIt[it]  = s;
        cIt[it]  = e & 63;
        gRow[it] = (s >> 4) * 128 + (s & 15);   // global row sans tile*16
    }
    float4 ld[4];

#define ISSUE(T)                                                              \
    do {                                                                      \
        _Pragma("unroll")                                                     \
        for (int it = 0; it < 4; ++it)                                        \
            ld[it] = *(const float4*)(xg + (size_t)(gRow[it] + (T) * 16) * IND + cIt[it]); \
    } while (0)

#define XWRITE()                                                              \
    do {                                                                      \
        _Pragma("unroll")                                                     \
        for (int it = 0; it < 4; ++it) {                                      \
            ushort4 w4;                                                       \
            w4.x = f2bf(ld[it].x); w4.y = f2bf(ld[it].y);                     \
            w4.z = f2bf(ld[it].z); w4.w = f2bf(ld[it].w);                     \
            *(ushort4*)(&xbt[sIt[it] * XBS + cIt[it]]) = w4;                  \
        }                                                                     \
    } while (0)

    // ---- weight fragments (loads overlap the tile-0/1 staging) ----
    bf16x8 w1f[2];
#pragma unroll
    for (int ks = 0; ks < 2; ++ks)
        w1f[ks] = *(const bf16x8*)(wt + (ot * 16 + r) * 64 + ks * 32 + q * 8);

    const unsigned short* w2t = wt + 8192;
    bf16x8 w2f[4];
#pragma unroll
    for (int ks = 0; ks < 4; ++ks)
        w2f[ks] = *(const bf16x8*)(w2t + (ot * 16 + r) * 128 + ks * 32 + q * 8);

    const float4 b1s = *(const float4*)(bl1 + ot * 16 + q * 4);
    const float4 b2s = *(const float4*)(bl2 + ot * 16 + q * 4);

    // ---- prologue: team tile (team) staged; tile (team+2) in regs ----
    ISSUE(team);
    XWRITE();
    ISSUE(team + 2);
    __syncthreads();

    // ======================= phase A: 4 iterations x 2 tiles ================
    ushort4 aggv[4];   // bf16-packed agg slice per processed tile

#pragma unroll
    for (int i = 0; i < 4; ++i) {
        // ---- layer 1 (K=64), all 8 perturbations of tile 2i+team ----
#pragma unroll
        for (int p = 0; p < PP; ++p) {
            f32x4 a0 = (f32x4){0.f, 0.f, 0.f, 0.f};
#pragma unroll
            for (int ks = 0; ks < 2; ++ks) {
                bf16x8 xf = *(const bf16x8*)(&xbt[(p * 16 + r) * XBS + ks * 32 + q * 8]);
                a0 = mfma16(w1f[ks], xf, a0);
            }
            ushort4 v0;
            v0.x = f2bf(fmaxf(a0[0] + b1s.x, 0.f));
            v0.y = f2bf(fmaxf(a0[1] + b1s.y, 0.f));
            v0.z = f2bf(fmaxf(a0[2] + b1s.z, 0.f));
            v0.w = f2bf(fmaxf(a0[3] + b1s.w, 0.f));
            *(ushort4*)(&h1t[(p * 16 + r) * LSTR + ot * 16 + q * 4]) = v0;
        }

        __syncthreads();   // h1t complete; xbt reads done -> rewritable

        // ---- layer 2 (K=128), relu-accumulate over perturbations -> regs ----
        f32x4 agg0 = (f32x4){0.f, 0.f, 0.f, 0.f};
#pragma unroll
        for (int p = 0; p < PP; ++p) {
            f32x4 c0 = (f32x4){0.f, 0.f, 0.f, 0.f};
#pragma unroll
            for (int ks = 0; ks < 4; ++ks) {
                bf16x8 hf = *(const bf16x8*)(&h1t[(p * 16 + r) * LSTR + ks * 32 + q * 8]);
                c0 = mfma16(w2f[ks], hf, c0);
            }
            agg0[0] += fmaxf(c0[0] + b2s.x, 0.f);
            agg0[1] += fmaxf(c0[1] + b2s.y, 0.f);
            agg0[2] += fmaxf(c0[2] + b2s.z, 0.f);
            agg0[3] += fmaxf(c0[3] + b2s.w, 0.f);
        }
        aggv[i].x = f2bf(agg0[0]);
        aggv[i].y = f2bf(agg0[1]);
        aggv[i].z = f2bf(agg0[2]);
        aggv[i].w = f2bf(agg0[3]);

        // stage next tile into xbt (safe: last readers synced at the barrier
        // above); refill regs one iteration (=2 tiles) ahead.
        if (i < 3) XWRITE();
        if (i < 2) ISSUE(2 * (i + 2) + team);

        __syncthreads();   // h1t rewritable next iter; xbt staged
    }

    // materialize agg into h1a: team t wrote tiles 2i+t -> disjoint rows;
    // last h1a readers (team 0's L2, i=3) synced at the final barrier above.
#pragma unroll
    for (int i = 0; i < 4; ++i)
        *(ushort4*)(&h1a[((2 * i + team) * 16 + r) * LSTR + ot * 16 + q * 4]) = aggv[i];
    __syncthreads();

    // ================= phase B: 4x (Linear+ReLU) + pool (team 0) ===========
    int cur = 0;
#pragma unroll
    for (int l = 0; l < 4; ++l) {
        if (team == 0) {
            const unsigned short* wl = wt + 24576 + l * 16384;
            const float* bl = (l == 0) ? bg1 : (l == 1) ? bg2 : (l == 2) ? bb1 : bb2;

            bf16x8 wf[4];
#pragma unroll
            for (int ks = 0; ks < 4; ++ks)
                wf[ks] = *(const bf16x8*)(wl + (ot * 16 + r) * 128 + ks * 32 + q * 8);

            unsigned short* Xb = cur ? h1b : h1a;
            unsigned short* Yb = cur ? h1a : h1b;

            f32x4 acc[8];
#pragma unroll
            for (int j = 0; j < 8; ++j)
                acc[j] = (f32x4){0.f, 0.f, 0.f, 0.f};

#pragma unroll
            for (int ks = 0; ks < 4; ++ks) {
#pragma unroll
                for (int j = 0; j < 8; ++j) {
                    bf16x8 xf = *(const bf16x8*)(&Xb[(j * 16 + r) * LSTR + ks * 32 + q * 8]);
                    acc[j] = mfma16(wf[ks], xf, acc[j]);
                }
            }

            if (l < 3) {
                float4 bs = *(const float4*)(bl + ot * 16 + q * 4);
#pragma unroll
                for (int j = 0; j < 8; ++j) {
                    ushort4 v;
                    v.x = f2bf(fmaxf(acc[j][0] + bs.x, 0.f));
                    v.y = f2bf(fmaxf(acc[j][1] + bs.y, 0.f));
                    v.z = f2bf(fmaxf(acc[j][2] + bs.z, 0.f));
                    v.w = f2bf(fmaxf(acc[j][3] + bs.w, 0.f));
                    *(ushort4*)(&Yb[(j * 16 + r) * LSTR + ot * 16 + q * 4]) = v;
                }
            } else {
                float4 bs = *(const float4*)(bl + ot * 16 + q * 4);
                float s0 = 0.f, s1 = 0.f, s2 = 0.f, s3 = 0.f;
#pragma unroll
                for (int j = 0; j < 8; ++j) {
                    s0 += fmaxf(acc[j][0] + bs.x, 0.f);
                    s1 += fmaxf(acc[j][1] + bs.y, 0.f);
                    s2 += fmaxf(acc[j][2] + bs.z, 0.f);
                    s3 += fmaxf(acc[j][3] + bs.w, 0.f);
                }
#pragma unroll
                for (int m = 1; m < 16; m <<= 1) {
                    s0 += __shfl_xor(s0, m, 64);
                    s1 += __shfl_xor(s1, m, 64);
                    s2 += __shfl_xor(s2, m, 64);
                    s3 += __shfl_xor(s3, m, 64);
                }
                if (r == 0) {
                    pool[ot * 16 + q * 4 + 0] = s0;   // exclusive cols per wave
                    pool[ot * 16 + q * 4 + 1] = s1;
                    pool[ot * 16 + q * 4 + 2] = s2;
                    pool[ot * 16 + q * 4 + 3] = s3;
                }
            }
        }
        if (l < 3) __syncthreads();   // block-wide: team 1 idles through
        cur ^= 1;
    }
    __syncthreads();

    // ===================== decoder + log_softmax ===========================
    if (tid < 64) {
        float a0 = bd1[tid], a1 = 0.f, a2 = 0.f, a3 = 0.f;
#pragma unroll
        for (int k = 0; k < 128; k += 4) {
            a0 += pool[k]     * Wd1[(k)     * 64 + tid];
            a1 += pool[k + 1] * Wd1[(k + 1) * 64 + tid];
            a2 += pool[k + 2] * Wd1[(k + 2) * 64 + tid];
            a3 += pool[k + 3] * Wd1[(k + 3) * 64 + tid];
        }
        z[tid] = fmaxf((a0 + a1) + (a2 + a3), 0.f);
    }
    __syncthreads();
    if (tid < OUTD) {
        float b0 = bd2[tid], b1 = 0.f;
#pragma unroll
        for (int k = 0; k < 64; k += 2) {
            b0 += z[k]     * Wd2[(k)     * OUTD + tid];
            b1 += z[k + 1] * Wd2[(k + 1) * OUTD + tid];
        }
        zz[tid] = b0 + b1;
    }
    __syncthreads();
    if (tid == 0) {
        float m = -1e30f;
#pragma unroll
        for (int j = 0; j < OUTD; ++j) m = fmaxf(m, zz[j]);
        float ssum = 0.f;
#pragma unroll
        for (int j = 0; j < OUTD; ++j) ssum += expf(zz[j] - m);
        float ls = logf(ssum);
#pragma unroll
        for (int j = 0; j < OUTD; ++j) out[g * OUTD + j] = zz[j] - m - ls;
    }
#undef ISSUE
#undef XWRITE
}

extern "C" void kernel_launch(void* const* d_in, const int* in_sizes, int n_in,
                              void* d_out, int out_size, void* d_ws, size_t ws_size,
                              hipStream_t stream) {
    const float* x   = (const float*)d_in[0];
    // d_in[1] = ptr (unused; structure is static)
    const float* Wl1 = (const float*)d_in[2];
    const float* bl1 = (const float*)d_in[3];
    const float* Wl2 = (const float*)d_in[4];
    const float* bl2 = (const float*)d_in[5];
    const float* Wg1 = (const float*)d_in[6];
    const float* bg1 = (const float*)d_in[7];
    const float* Wg2 = (const float*)d_in[8];
    const float* bg2 = (const float*)d_in[9];
    const float* Wb1 = (const float*)d_in[10];
    const float* bb1 = (const float*)d_in[11];
    const float* Wb2 = (const float*)d_in[12];
    const float* bb2 = (const float*)d_in[13];
    const float* Wd1 = (const float*)d_in[14];
    const float* bd1 = (const float*)d_in[15];
    const float* Wd2 = (const float*)d_in[16];
    const float* bd2 = (const float*)d_in[17];

    unsigned short* ws = (unsigned short*)d_ws;

    prep_weights<<<352, 256, 0, stream>>>(Wl1, Wl2, Wg1, Wg2, Wb1, Wb2, ws);
    graph_fused<<<NG, 1024, 0, stream>>>(x, ws, bl1, bl2, bg1, bg2, bb1, bb2,
                                         Wd1, bd1, Wd2, bd2, (float*)d_out);
}